// Round 18
// baseline (1020.746 us; speedup 1.0000x reference)
//
#include <hip/hip_runtime.h>
#include <hip/hip_bf16.h>

typedef _Float16 f16;
typedef _Float16 f16x8 __attribute__((ext_vector_type(8)));
typedef _Float16 f16x4v __attribute__((ext_vector_type(4)));
typedef _Float16 h2 __attribute__((ext_vector_type(2)));
typedef float f32x4 __attribute__((ext_vector_type(4)));
typedef unsigned ui4v __attribute__((ext_vector_type(4)));
typedef unsigned short u16x4 __attribute__((ext_vector_type(4)));
typedef unsigned long long ull;

#define B_ 8
#define S_ 512
#define H_ 768
#define V_ 35004
#define J_ 30
#define K_ 9
#define R_ 2160          // out rows, r = b*270 + j*9 + t
#define H3 2304
#define VMT 17           // vocab M tiles
#define VNT 274          // vocab N tiles
#define CASTB 864        // extra blocks in k_prep for wih cast
#define VH0 17504        // fin3 half-0 length (16-aligned); half-1 = 17500

#define ALD(p) __hip_atomic_load((p), __ATOMIC_RELAXED, __HIP_MEMORY_SCOPE_AGENT)
#define AST(p, v) __hip_atomic_store((p), (v), __ATOMIC_RELAXED, __HIP_MEMORY_SCOPE_AGENT)

// ---------------------------------------------------------------- prep kernels

// rows < R_: build W_all; rows >= R_: cast wih -> f16
__global__ void k_prep(const float* __restrict__ emb, const float* __restrict__ dec,
                       const int* __restrict__ teacher, f16* __restrict__ Wall,
                       const float* __restrict__ wih, f16* __restrict__ wih16) {
    int r = blockIdx.x;
    if (r < R_) {
        int b = r / 270, s = r % 270, j = s / 9, t = s % 9;
        const float* src = (t == 0) ? dec + ((long)b * J_ + j) * H_
                                    : emb + (long)teacher[((long)b * J_ + j) * K_ + (t - 1)] * H_;
        f16* dst = Wall + (long)r * H_;
        for (int c = threadIdx.x; c < H_; c += 256) dst[c] = (f16)src[c];
    } else {
        const long n = (long)H3 * H_;
        for (long i = (long)(r - R_) * 256 + threadIdx.x; i < n; i += (long)CASTB * 256)
            wih16[i] = (f16)wih[i];
    }
}

// h exchange word: {seq:32 | f32 bits:32}; chain-major [chain][parity][768].
// Writes BOTH parities every call (replay-deterministic).
__global__ void k_init_h(const float* __restrict__ hidden, ull* __restrict__ hbuf) {
    int i = blockIdx.x * 256 + threadIdx.x;
    if (i < B_ * H_) {
        int b = i / H_, u = i % H_;
        hbuf[(long)b * 1536 + u] = (ull)__float_as_uint(hidden[i]);  // seq 0, parity 0
        hbuf[(long)b * 1536 + 768 + u] = 0;                          // parity 1 cleared
    }
}

// ---------------------------------------------------------------- shared GEMM helpers
typedef const __attribute__((address_space(1))) unsigned GASU;
typedef __attribute__((address_space(3))) unsigned LASU;
__device__ __forceinline__ void gld16(const f16* g, f16* l) {
    __builtin_amdgcn_global_load_lds((GASU*)g, (LASU*)l, 16, 0, 0);
}

// ---------------------------------------------------------------- f16 MFMA GEMM (m97 structure)
// C[M,N] = A[M,K] @ B[N,K]^T ; MODE 0: store, 1: store + bias[col]
template <int MODE>
__global__ __launch_bounds__(256) void k_gemm(const f16* __restrict__ A, const f16* __restrict__ Bm,
                                              float* __restrict__ C, const float* __restrict__ bias,
                                              int M, int N, int K, long sA, long sB, long sC) {
    A += (long)blockIdx.z * sA;
    Bm += (long)blockIdx.z * sB;
    C += (long)blockIdx.z * sC;
    const int m0 = blockIdx.y * 128, n0 = blockIdx.x * 128;
    __shared__ f16 As[128 * 32];
    __shared__ f16 Bs[128 * 32];
    const int tid = threadIdx.x, lane = tid & 63, wave = tid >> 6;
    const int wm = wave >> 1, wn = wave & 1;
    const int fr = lane & 15, kg = lane >> 4;
    f32x4 acc[4][4] = {};
    const int idxu = wave * 128;
    const int i0 = idxu + lane, i1 = idxu + 64 + lane;
    const int r0 = i0 >> 2, k80 = i0 & 3;
    const int r1 = i1 >> 2, k81 = i1 & 3;
    int ga0 = m0 + r0; if (ga0 >= M) ga0 = M - 1;
    int ga1 = m0 + r1; if (ga1 >= M) ga1 = M - 1;
    int gb0 = n0 + r0; if (gb0 >= N) gb0 = N - 1;
    int gb1 = n0 + r1; if (gb1 >= N) gb1 = N - 1;
    const f16* pa0 = A + (long)ga0 * K + k80 * 8;
    const f16* pa1 = A + (long)ga1 * K + k81 * 8;
    const f16* pb0 = Bm + (long)gb0 * K + k80 * 8;
    const f16* pb1 = Bm + (long)gb1 * K + k81 * 8;
    for (int kt = 0; kt < K; kt += 32) {
        gld16(pa0 + kt, As + idxu * 8);
        gld16(pa1 + kt, As + idxu * 8 + 512);
        gld16(pb0 + kt, Bs + idxu * 8);
        gld16(pb1 + kt, Bs + idxu * 8 + 512);
        __syncthreads();
        f16x8 af[4], bf[4];
#pragma unroll
        for (int m = 0; m < 4; ++m) af[m] = *(const f16x8*)(As + (wm * 64 + m * 16 + fr) * 32 + kg * 8);
#pragma unroll
        for (int n = 0; n < 4; ++n) bf[n] = *(const f16x8*)(Bs + (wn * 64 + n * 16 + fr) * 32 + kg * 8);
#pragma unroll
        for (int m = 0; m < 4; ++m)
#pragma unroll
            for (int n = 0; n < 4; ++n)
                acc[m][n] = __builtin_amdgcn_mfma_f32_16x16x32_f16(af[m], bf[n], acc[m][n], 0, 0, 0);
        __syncthreads();
    }
    const int crow = m0 + wm * 64 + (lane >> 4) * 4;
    const int ccol = n0 + wn * 64 + fr;
#pragma unroll
    for (int n = 0; n < 4; ++n) {
        int col = ccol + n * 16;
        if (col >= N) continue;
        float bv = (MODE == 1) ? bias[col] : 0.f;
#pragma unroll
        for (int m = 0; m < 4; ++m) {
#pragma unroll
            for (int q = 0; q < 4; ++q) {
                int row = crow + m * 16 + q;
                if (row < M) C[(long)row * N + col] = acc[m][n][q] + bv;
            }
        }
    }
}

// ---------------------------------------------------------------- merged hi/lo attention logits
__global__ __launch_bounds__(256) void k_attn3(const f16* __restrict__ Ahi, const f16* __restrict__ Alo,
                                               const f16* __restrict__ Bhi, const f16* __restrict__ Blo,
                                               float* __restrict__ C, int M, int N, int K,
                                               long sA, long sB, long sC) {
    const long za = (long)blockIdx.z * sA, zb = (long)blockIdx.z * sB;
    C += (long)blockIdx.z * sC;
    const int m0 = blockIdx.y * 128, n0 = blockIdx.x * 128;
    __shared__ f16 As[128 * 32];
    __shared__ f16 Bs[128 * 32];
    const int tid = threadIdx.x, lane = tid & 63, wave = tid >> 6;
    const int wm = wave >> 1, wn = wave & 1;
    const int fr = lane & 15, kg = lane >> 4;
    f32x4 acc[4][4] = {};
    const int idxu = wave * 128;
    const int i0 = idxu + lane, i1 = idxu + 64 + lane;
    const int r0 = i0 >> 2, k80 = i0 & 3;
    const int r1 = i1 >> 2, k81 = i1 & 3;
    int ga0 = m0 + r0; if (ga0 >= M) ga0 = M - 1;
    int ga1 = m0 + r1; if (ga1 >= M) ga1 = M - 1;
    int gb0 = n0 + r0; if (gb0 >= N) gb0 = N - 1;
    int gb1 = n0 + r1; if (gb1 >= N) gb1 = N - 1;
    const long oa0 = (long)ga0 * K + k80 * 8, oa1 = (long)ga1 * K + k81 * 8;
    const long ob0 = (long)gb0 * K + k80 * 8, ob1 = (long)gb1 * K + k81 * 8;
    for (int ph = 0; ph < 3; ++ph) {
        const f16* Ap = (ph == 2 ? Alo : Ahi) + za;
        const f16* Bp = (ph == 1 ? Blo : Bhi) + zb;
        for (int kt = 0; kt < K; kt += 32) {
            gld16(Ap + oa0 + kt, As + idxu * 8);
            gld16(Ap + oa1 + kt, As + idxu * 8 + 512);
            gld16(Bp + ob0 + kt, Bs + idxu * 8);
            gld16(Bp + ob1 + kt, Bs + idxu * 8 + 512);
            __syncthreads();
            f16x8 af[4], bf[4];
#pragma unroll
            for (int m = 0; m < 4; ++m) af[m] = *(const f16x8*)(As + (wm * 64 + m * 16 + fr) * 32 + kg * 8);
#pragma unroll
            for (int n = 0; n < 4; ++n) bf[n] = *(const f16x8*)(Bs + (wn * 64 + n * 16 + fr) * 32 + kg * 8);
#pragma unroll
            for (int m = 0; m < 4; ++m)
#pragma unroll
                for (int n = 0; n < 4; ++n)
                    acc[m][n] = __builtin_amdgcn_mfma_f32_16x16x32_f16(af[m], bf[n], acc[m][n], 0, 0, 0);
            __syncthreads();
        }
    }
    const int crow = m0 + wm * 64 + (lane >> 4) * 4;
    const int ccol = n0 + wn * 64 + fr;
#pragma unroll
    for (int n = 0; n < 4; ++n) {
        int col = ccol + n * 16;
        if (col >= N) continue;
#pragma unroll
        for (int m = 0; m < 4; ++m) {
#pragma unroll
            for (int q = 0; q < 4; ++q) {
                int row = crow + m * 16 + q;
                if (row < M) C[(long)row * N + col] = acc[m][n][q];
            }
        }
    }
}

// ---------------------------------------------------------------- vocab GEMM
// BF16OUT=0: Cf = exp(...) f32. BF16OUT=1: Ch = bf16(exp(...)) u16.
// Both: per-tile row partial sums (f32, pre-rounding) -> psum[nt][row].
template <int BF16OUT>
__global__ __launch_bounds__(256) void k_vocab(const f16* __restrict__ A, const f16* __restrict__ Bm,
                                               float* __restrict__ Cf, unsigned short* __restrict__ Ch,
                                               float* __restrict__ psum) {
    const int M = R_, N = V_, K = H_;
    const int nwg = VMT * VNT;
    int lin = blockIdx.x;
    int q8 = nwg / 8, r8 = nwg % 8;
    int xcd = lin & 7, idx = lin >> 3;
    int newlin = (xcd < r8) ? xcd * (q8 + 1) + idx : r8 * (q8 + 1) + (xcd - r8) * q8 + idx;
    int mt = newlin % VMT, nt = newlin / VMT;
    const int m0 = mt * 128, n0 = nt * 128;
    __shared__ f16 As[128 * 32];
    __shared__ f16 Bs[128 * 32];
    __shared__ float rpart[2][128];
    const int tid = threadIdx.x, lane = tid & 63, wave = tid >> 6;
    const int wm = wave >> 1, wn = wave & 1;
    const int fr = lane & 15, kg = lane >> 4;
    f32x4 acc[4][4] = {};
    const int idxu = wave * 128;
    const int i0 = idxu + lane, i1 = idxu + 64 + lane;
    const int r0 = i0 >> 2, k80 = i0 & 3;
    const int r1 = i1 >> 2, k81 = i1 & 3;
    int ga0 = m0 + r0; if (ga0 >= M) ga0 = M - 1;
    int ga1 = m0 + r1; if (ga1 >= M) ga1 = M - 1;
    int gb0 = n0 + r0; if (gb0 >= N) gb0 = N - 1;
    int gb1 = n0 + r1; if (gb1 >= N) gb1 = N - 1;
    const f16* pa0 = A + (long)ga0 * K + k80 * 8;
    const f16* pa1 = A + (long)ga1 * K + k81 * 8;
    const f16* pb0 = Bm + (long)gb0 * K + k80 * 8;
    const f16* pb1 = Bm + (long)gb1 * K + k81 * 8;
    for (int kt = 0; kt < K; kt += 32) {
        gld16(pa0 + kt, As + idxu * 8);
        gld16(pa1 + kt, As + idxu * 8 + 512);
        gld16(pb0 + kt, Bs + idxu * 8);
        gld16(pb1 + kt, Bs + idxu * 8 + 512);
        __syncthreads();
        f16x8 af[4], bf[4];
#pragma unroll
        for (int m = 0; m < 4; ++m) af[m] = *(const f16x8*)(As + (wm * 64 + m * 16 + fr) * 32 + kg * 8);
#pragma unroll
        for (int n = 0; n < 4; ++n) bf[n] = *(const f16x8*)(Bs + (wn * 64 + n * 16 + fr) * 32 + kg * 8);
#pragma unroll
        for (int m = 0; m < 4; ++m)
#pragma unroll
            for (int n = 0; n < 4; ++n)
                acc[m][n] = __builtin_amdgcn_mfma_f32_16x16x32_f16(af[m], bf[n], acc[m][n], 0, 0, 0);
        __syncthreads();
    }
    const int crow = m0 + wm * 64 + (lane >> 4) * 4;
    const int ccol = n0 + wn * 64 + fr;
    float rs[4][4];
#pragma unroll
    for (int m = 0; m < 4; ++m)
#pragma unroll
        for (int q = 0; q < 4; ++q) rs[m][q] = 0.f;
#pragma unroll
    for (int n = 0; n < 4; ++n) {
        int col = ccol + n * 16;
        if (col >= N) continue;
#pragma unroll
        for (int m = 0; m < 4; ++m) {
#pragma unroll
            for (int q = 0; q < 4; ++q) {
                int row = crow + m * 16 + q;
                if (row < M) {
                    float e = __expf(acc[m][n][q]);
                    if (BF16OUT) {
                        unsigned uu = __float_as_uint(e);
                        uu += 0x7FFFu + ((uu >> 16) & 1u);   // RNE to bf16
                        Ch[(long)row * N + col] = (unsigned short)(uu >> 16);
                    } else {
                        Cf[(long)row * N + col] = e;
                    }
                    rs[m][q] += e;
                }
            }
        }
    }
#pragma unroll
    for (int m = 0; m < 4; ++m)
#pragma unroll
        for (int q = 0; q < 4; ++q) {
            float v = rs[m][q];
            v += __shfl_xor(v, 1);
            v += __shfl_xor(v, 2);
            v += __shfl_xor(v, 4);
            v += __shfl_xor(v, 8);
            rs[m][q] = v;
        }
    if ((lane & 15) == 0) {
#pragma unroll
        for (int m = 0; m < 4; ++m)
#pragma unroll
            for (int q = 0; q < 4; ++q)
                rpart[wn][wm * 64 + (lane >> 4) * 4 + m * 16 + q] = rs[m][q];
    }
    __syncthreads();
    if (tid < 128) {
        int row = m0 + tid;
        if (row < M) psum[(long)nt * M + row] = rpart[0][tid] + rpart[1][tid];
    }
}

// ---------------------------------------------------------------- GRU recurrence + hidden preps
// Shuffle-reduced finisher: thread (unit=tid>>3, j=tid&7) accumulates k-slices
// {j*8+i*64}; 3-step shfl_xor over the 8-lane group finishes the dot; lane j==0
// computes gates/stores. ONE barrier/step; hsf parity-double-buffered (write at
// s+2 is after barrier(s+1), which is after all FMA(s) reads -> race-free).
__device__ __forceinline__ float fd2(unsigned hv, unsigned wv, float acc) {
#if __has_builtin(__builtin_amdgcn_fdot2)
    return __builtin_amdgcn_fdot2(__builtin_bit_cast(h2, hv), __builtin_bit_cast(h2, wv), acc, false);
#else
    h2 a = __builtin_bit_cast(h2, hv), b = __builtin_bit_cast(h2, wv);
    return acc + (float)a.x * (float)b.x + (float)a.y * (float)b.y;
#endif
}

__global__ __launch_bounds__(256, 1) void k_gru(const float* __restrict__ gi,
                                                const float* __restrict__ whh,
                                                const float* __restrict__ bhh,
                                                ull* hbuf,
                                                f16* __restrict__ Hhi, f16* __restrict__ Hlo,
                                                const float* __restrict__ emb, f16* __restrict__ emb16,
                                                const float* __restrict__ enc, f16* __restrict__ ehi,
                                                f16* __restrict__ elo, f16* __restrict__ encT) {
    __shared__ ui4v wsvu[9216];               // weights (recurrence) / transpose tile (prep)
    __shared__ __align__(16) f16 hsf[2][768]; // parity double-buffered h staging
    const int tid = threadIdx.x;
    if (blockIdx.x >= 192) {
        // ---------- hidden prep on idle CUs ----------
        const long pt = (long)(blockIdx.x - 192) * 256 + tid;
        const long n4 = (long)V_ * H_ / 4;
        for (long i = pt; i < n4; i += 64 * 256) {
            f32x4 v = ((const f32x4*)emb)[i];
            f16x4v r = {(f16)v.x, (f16)v.y, (f16)v.z, (f16)v.w};
            ((f16x4v*)emb16)[i] = r;
        }
        const long n4e = (long)B_ * S_ * H_ / 4;
        for (long i = pt; i < n4e; i += 64 * 256) {
            f32x4 v = ((const f32x4*)enc)[i];
            f16 h0 = (f16)v.x, h1 = (f16)v.y, h2v = (f16)v.z, h3 = (f16)v.w;
            f16x4v hv = {h0, h1, h2v, h3};
            ((f16x4v*)ehi)[i] = hv;
            f16x4v lv = {(f16)(v.x - (float)h0), (f16)(v.y - (float)h1),
                         (f16)(v.z - (float)h2v), (f16)(v.w - (float)h3)};
            ((f16x4v*)elo)[i] = lv;
        }
        // encT via LDS-tiled transpose (64x64 f32 tile, pad 65)
        float* tl = (float*)wsvu;
        for (int t = blockIdx.x - 192; t < 8 * 8 * 12; t += 64) {
            int ht = t % 12, st = (t / 12) % 8, bb = t / 96;
            __syncthreads();
#pragma unroll
            for (int k = 0; k < 16; ++k) {
                int i = tid + k * 256;
                int sl = i >> 6, hl = i & 63;
                tl[sl * 65 + hl] = enc[((long)bb * S_ + st * 64 + sl) * H_ + ht * 64 + hl];
            }
            __syncthreads();
#pragma unroll
            for (int k = 0; k < 16; ++k) {
                int i = tid + k * 256;
                int hl = i >> 6, sl = i & 63;
                encT[((long)bb * H_ + ht * 64 + hl) * S_ + st * 64 + sl] = (f16)tl[sl * 65 + hl];
            }
        }
        return;
    }
    // ---------- recurrence ----------
    const int chain = blockIdx.x / 24;
    const int blk = blockIdx.x % 24;
    const int u0 = blk * 32;
    for (int idx = tid; idx < 9216; idx += 256) {
        int uu = idx & 31, k8 = (idx >> 5) % 96, g = idx / (96 * 32);
        const float* src = whh + (long)(g * H_ + u0 + uu) * H_ + k8 * 8;
        f32x4 a = *(const f32x4*)src;
        f32x4 b2 = *(const f32x4*)(src + 4);
        f16x8 pk = {(f16)a.x, (f16)a.y, (f16)a.z, (f16)a.w,
                    (f16)b2.x, (f16)b2.y, (f16)b2.z, (f16)b2.w};
        wsvu[idx] = __builtin_bit_cast(ui4v, pk);
    }
    const int unit = tid >> 3, j = tid & 7, lane = tid & 63;
    const bool fin = (j == 0);
    float b_r = 0.f, b_z = 0.f, b_n = 0.f;
    if (fin) {
        int c = u0 + unit;
        b_r = bhh[c];
        b_z = bhh[H_ + c];
        b_n = bhh[2 * H_ + c];
    }
    __syncthreads();
    const int pw = (tid >> 6) * 192 + lane;   // this wave's h-word base
    ui4v wreg[3][12];                         // chunk k8 = j + i*8
#pragma unroll
    for (int g = 0; g < 3; ++g)
#pragma unroll
        for (int i = 0; i < 12; ++i)
            wreg[g][i] = wsvu[(g * 96 + j + i * 8) * 32 + unit];
    ull* base = hbuf + (long)chain * 1536;
    float g0 = 0.f, g1 = 0.f, g2v = 0.f;
    if (fin) {
        const float* gp = gi + (long)chain * 270 * H3;
        int c = u0 + unit;
        g0 = gp[c];
        g1 = gp[H_ + c];
        g2v = gp[2 * H_ + c];
    }
    for (int s = 0; s < 270; ++s) {
        const ull* rb = base + (s & 1) * 768;
        ull* wb = base + ((s + 1) & 1) * 768;
        const unsigned want = (unsigned)s;
        const int par = s & 1;
        ull v0, v1, v2, vh = 0;
        for (;;) {
            v0 = ALD(rb + pw);
            v1 = ALD(rb + pw + 64);
            v2 = ALD(rb + pw + 128);
            bool ok = ((unsigned)(v0 >> 32) == want) & ((unsigned)(v1 >> 32) == want) &
                      ((unsigned)(v2 >> 32) == want);
            if (fin) {
                vh = ALD(rb + u0 + unit);
                ok &= ((unsigned)(vh >> 32) == want);
            }
            if (ok) break;
        }
        hsf[par][pw] = (f16)__uint_as_float((unsigned)v0);
        hsf[par][pw + 64] = (f16)__uint_as_float((unsigned)v1);
        hsf[par][pw + 128] = (f16)__uint_as_float((unsigned)v2);
        __syncthreads();                       // staging complete (only barrier/step)
        float ar = 0.f, az = 0.f, an = 0.f;
#pragma unroll
        for (int i = 0; i < 12; ++i) {
            ui4v hv = *(const ui4v*)(&hsf[par][(j + i * 8) * 8]);
            ui4v wr = wreg[0][i], wz = wreg[1][i], wn = wreg[2][i];
            ar = fd2(hv.x, wr.x, ar); ar = fd2(hv.y, wr.y, ar);
            ar = fd2(hv.z, wr.z, ar); ar = fd2(hv.w, wr.w, ar);
            az = fd2(hv.x, wz.x, az); az = fd2(hv.y, wz.y, az);
            az = fd2(hv.z, wz.z, az); az = fd2(hv.w, wz.w, az);
            an = fd2(hv.x, wn.x, an); an = fd2(hv.y, wn.y, an);
            an = fd2(hv.z, wn.z, an); an = fd2(hv.w, wn.w, an);
        }
        // 8-lane butterfly: unit total lands in lane j==0 of each group
        ar += __shfl_xor(ar, 1); az += __shfl_xor(az, 1); an += __shfl_xor(an, 1);
        ar += __shfl_xor(ar, 2); az += __shfl_xor(az, 2); an += __shfl_xor(an, 2);
        ar += __shfl_xor(ar, 4); az += __shfl_xor(az, 4); an += __shfl_xor(an, 4);
        if (fin) {
            float gr = ar + b_r, gz = az + b_z, gn = an + b_n;
            float hold = __uint_as_float((unsigned)vh);
            float rg = 1.f / (1.f + __expf(-(g0 + gr)));
            float zg = 1.f / (1.f + __expf(-(g1 + gz)));
            float xa = g2v + rg * gn;
            float e2 = __expf(-2.f * xa);
            float ng = (1.f - e2) / (1.f + e2);
            float hnew = (1.f - zg) * ng + zg * hold;
            int c = u0 + unit;
            ull wvv = ((ull)(unsigned)(s + 1) << 32) | (ull)__float_as_uint(hnew);
            AST(wb + c, wvv);
            long row = (long)chain * 270 + s;
            f16 h16 = (f16)hnew;
            Hhi[row * H_ + c] = h16;
            Hlo[row * H_ + c] = (f16)(hnew - (float)h16);
            if (s < 269) {   // prefetch next step's gi (hidden behind next poll)
                const float* gp = gi + ((long)chain * 270 + s + 1) * H3;
                g0 = gp[c];
                g1 = gp[H_ + c];
                g2v = gp[2 * H_ + c];
            }
        }
    }
}

// ---------------------------------------------------------------- attention softmax
__global__ __launch_bounds__(256) void k_attn_softmax(const float* __restrict__ lg,
                                                      const int* __restrict__ x, f16* __restrict__ ah) {
    __shared__ float red[256];
    int r = blockIdx.x, tid = threadIdx.x;
    int b = r / 270;
    const float* lr = lg + (long)r * S_;
    const int* xb = x + (long)b * S_;
    float v0 = lr[tid];
    if (xb[tid] == 0) v0 = -1e9f;
    float v1 = lr[tid + 256];
    if (xb[tid + 256] == 0) v1 = -1e9f;
    red[tid] = fmaxf(v0, v1);
    __syncthreads();
    for (int o = 128; o > 0; o >>= 1) {
        if (tid < o) red[tid] = fmaxf(red[tid], red[tid + o]);
        __syncthreads();
    }
    float m = red[0];
    __syncthreads();
    float e0 = __expf(v0 - m), e1 = __expf(v1 - m);
    red[tid] = e0 + e1;
    __syncthreads();
    for (int o = 128; o > 0; o >>= 1) {
        if (tid < o) red[tid] += red[tid + o];
        __syncthreads();
    }
    float inv = 1.f / red[0];
    ah[(long)r * S_ + tid] = (f16)(e0 * inv);
    ah[(long)r * S_ + tid + 256] = (f16)(e1 * inv);
}

// ---------------------------------------------------------------- fused p_gen + rinv + finalize + scatter
// TWO blocks per row (half-row each, 70KB LDS -> 2 blocks/CU). BF16: read u16
// exp temp; else read f32 exp from out in place. Scatter predicated on v-range.
template <int BF16>
__global__ __launch_bounds__(256, 2) void k_fin3(float* __restrict__ out,
                                                 const float* __restrict__ psum,
                                                 const unsigned short* __restrict__ expv,
                                                 const f16* __restrict__ Wall,
                                                 const f16* __restrict__ Hhi,
                                                 const f16* __restrict__ Hlo,
                                                 const float* __restrict__ ctx,
                                                 const float* __restrict__ wg,
                                                 const float* __restrict__ wgb,
                                                 const f16* __restrict__ ah,
                                                 const int* __restrict__ x) {
    __shared__ float row[VH0];
    __shared__ float red[256], red2[256];
    const int r = blockIdx.x >> 1, half = blockIdx.x & 1;
    const int tid = threadIdx.x;
    const int b = r / 270;
    const int lo = half ? VH0 : 0;
    const int len = half ? (V_ - VH0) : VH0;      // 17500 / 17504, both %4==0
    float a = 0.f;
    for (int i = tid; i < H_; i += 256) {
        a += (float)Wall[(long)r * H_ + i] * wg[i];
        a += ((float)Hhi[(long)r * H_ + i] + (float)Hlo[(long)r * H_ + i]) * wg[H_ + i];
        a += ctx[(long)r * H_ + i] * wg[2 * H_ + i];
    }
    float s = 0.f;
    for (int i = tid; i < VNT; i += 256) s += psum[(long)i * R_ + r];
    red[tid] = s;
    red2[tid] = a;
    __syncthreads();
    for (int o = 128; o > 0; o >>= 1) {
        if (tid < o) {
            red[tid] += red[tid + o];
            red2[tid] += red2[tid + o];
        }
        __syncthreads();
    }
    const float pgv = 1.f / (1.f + __expf(-(red2[0] + wgb[0])));
    const float scale = pgv / red[0];
    const int n4 = len / 4;
    if (BF16) {
        const unsigned short* ep = expv + (long)r * V_ + lo;
        for (int i = tid; i < n4; i += 256) {
            u16x4 v = ((const u16x4*)ep)[i];
            f32x4 o;
            o.x = __uint_as_float((unsigned)v.x << 16) * scale;
            o.y = __uint_as_float((unsigned)v.y << 16) * scale;
            o.z = __uint_as_float((unsigned)v.z << 16) * scale;
            o.w = __uint_as_float((unsigned)v.w << 16) * scale;
            ((f32x4*)row)[i] = o;
        }
    } else {
        const float* op = out + (long)r * V_ + lo;
        for (int i = tid; i < n4; i += 256) {
            f32x4 v = ((const f32x4*)op)[i];
            v.x *= scale;
            v.y *= scale;
            v.z *= scale;
            v.w *= scale;
            ((f32x4*)row)[i] = v;
        }
    }
    __syncthreads();
    const float om = 1.f - pgv;
    for (int s2 = tid; s2 < S_; s2 += 256) {
        int xv = x[(long)b * S_ + s2];
        if (xv != 0 && xv >= lo && xv < lo + len) {
            float av = (float)ah[(long)r * S_ + s2];
            if (av != 0.f) atomicAdd(&row[xv - lo], om * av);
        }
    }
    __syncthreads();
    float* orow = out + (long)r * V_ + lo;
    for (int i = tid; i < n4; i += 256)
        ((f32x4*)orow)[i] = ((const f32x4*)row)[i];
}

// ---------------------------------------------------------------- host
extern "C" void kernel_launch(void* const* d_in, const int* in_sizes, int n_in, void* d_out,
                              int out_size, void* d_ws, size_t ws_size, hipStream_t stream) {
    (void)in_sizes; (void)n_in; (void)out_size;
    const int* x = (const int*)d_in[0];
    const float* dec = (const float*)d_in[1];
    const float* enc = (const float*)d_in[2];
    const float* hid = (const float*)d_in[3];
    const int* tea = (const int*)d_in[4];
    const float* emb = (const float*)d_in[6];
    const float* wih = (const float*)d_in[7];
    const float* whh = (const float*)d_in[8];
    const float* bih = (const float*)d_in[9];
    const float* bhh = (const float*)d_in[10];
    const float* wgw = (const float*)d_in[11];
    const float* wgb = (const float*)d_in[12];
    float* out = (float*)d_out;

    char* w = (char*)d_ws;
    size_t off = 0;
    auto alloc = [&](size_t bytes) {
        void* p = w + off;
        off = (off + bytes + 255) & ~(size_t)255;
        return p;
    };
    // ---- live-through-finalize buffers first ----
    ull* hbuf = (ull*)alloc(8 * 1536 * 8);
    f16* Wall = (f16*)alloc((size_t)R_ * H_ * 2);
    f16* Hhi = (f16*)alloc((size_t)R_ * H_ * 2);
    f16* Hlo = (f16*)alloc((size_t)R_ * H_ * 2);
    f16* emb16 = (f16*)alloc((size_t)V_ * H_ * 2);
    f16* ah = (f16*)alloc((size_t)R_ * S_ * 2);
    float* ctx = (float*)alloc((size_t)R_ * H_ * 4);
    float* psum = (float*)alloc((size_t)VNT * R_ * 4);
    // ---- dead-after-midpipe buffers (aliasable by expv) ----
    const size_t deadbase = off;
    f16* wih16 = (f16*)alloc((size_t)H3 * H_ * 2);
    float* giA = (float*)alloc((size_t)R_ * H3 * 4);
    f16* ehi = (f16*)alloc((size_t)B_ * S_ * H_ * 2);
    f16* elo = (f16*)alloc((size_t)B_ * S_ * H_ * 2);
    f16* encT = (f16*)alloc((size_t)B_ * H_ * S_ * 2);
    float* lgH = (float*)alloc((size_t)R_ * S_ * 4);
    // expv aliases the dead region (only used after all dead buffers retire)
    unsigned short* expv = (unsigned short*)(w + deadbase);
    const bool fused = (deadbase + (size_t)R_ * V_ * 2 <= ws_size);

    k_init_h<<<24, 256, 0, stream>>>(hid, hbuf);
    k_prep<<<R_ + CASTB, 256, 0, stream>>>(emb, dec, tea, Wall, wih, wih16);

    // gi = W_all @ w_ih^T + b_ih
    {
        dim3 g(H3 / 128, (R_ + 127) / 128, 1);
        k_gemm<1><<<g, 256, 0, stream>>>(Wall, wih16, giA, bih, R_, H3, H_, 0, 0, 0);
    }
    // recurrence (blocks 0-191) + hidden preps on idle CUs (blocks 192-255)
    k_gru<<<256, 256, 0, stream>>>(giA, whh, bhh, hbuf, Hhi, Hlo,
                                   emb, emb16, enc, ehi, elo, encT);

    // attention logits (merged hi/lo): Hhi*Ehi + Hhi*Elo + Hlo*Ehi
    {
        dim3 g(S_ / 128, 3, 8);
        k_attn3<<<g, 256, 0, stream>>>(Hhi, Hlo, ehi, elo, lgH, 270, S_, H_,
                                       270L * H_, (long)S_ * H_, 270L * S_);
    }
    k_attn_softmax<<<R_, 256, 0, stream>>>(lgH, x, ah);
    {
        dim3 g(H_ / 128, 3, 8);
        k_gemm<0><<<g, 256, 0, stream>>>(ah, encT, ctx, nullptr, 270, H_, S_, 270L * S_, (long)H_ * S_, 270L * H_);
    }

    if (fused) {
        k_vocab<1><<<VMT * VNT, 256, 0, stream>>>(Hhi, emb16, nullptr, expv, psum);
        k_fin3<1><<<2 * R_, 256, 0, stream>>>(out, psum, expv, Wall, Hhi, Hlo, ctx, wgw, wgb, ah, x);
    } else {
        k_vocab<0><<<VMT * VNT, 256, 0, stream>>>(Hhi, emb16, out, nullptr, psum);
        k_fin3<0><<<2 * R_, 256, 0, stream>>>(out, psum, nullptr, Wall, Hhi, Hlo, ctx, wgw, wgb, ah, x);
    }
}

// Round 19
// 1001.331 us; speedup vs baseline: 1.0194x; 1.0194x over previous
//
#include <hip/hip_runtime.h>
#include <hip/hip_bf16.h>

typedef _Float16 f16;
typedef _Float16 f16x8 __attribute__((ext_vector_type(8)));
typedef _Float16 f16x4v __attribute__((ext_vector_type(4)));
typedef _Float16 h2 __attribute__((ext_vector_type(2)));
typedef float f32x4 __attribute__((ext_vector_type(4)));
typedef unsigned ui4v __attribute__((ext_vector_type(4)));
typedef unsigned short u16x4 __attribute__((ext_vector_type(4)));
typedef unsigned long long ull;

#define B_ 8
#define S_ 512
#define H_ 768
#define V_ 35004
#define J_ 30
#define K_ 9
#define R_ 2160          // out rows, r = b*270 + j*9 + t
#define H3 2304
#define VMT 17           // vocab M tiles
#define VNT 274          // vocab N tiles
#define CASTB 864        // extra blocks in k_prep for wih cast
#define VH0 17504        // fin3 half-0 length (16-aligned); half-1 = 17500

#define ALD(p) __hip_atomic_load((p), __ATOMIC_RELAXED, __HIP_MEMORY_SCOPE_AGENT)
#define AST(p, v) __hip_atomic_store((p), (v), __ATOMIC_RELAXED, __HIP_MEMORY_SCOPE_AGENT)

// ---------------------------------------------------------------- prep kernels

// rows < R_: build W_all; rows >= R_: cast wih -> f16
__global__ void k_prep(const float* __restrict__ emb, const float* __restrict__ dec,
                       const int* __restrict__ teacher, f16* __restrict__ Wall,
                       const float* __restrict__ wih, f16* __restrict__ wih16) {
    int r = blockIdx.x;
    if (r < R_) {
        int b = r / 270, s = r % 270, j = s / 9, t = s % 9;
        const float* src = (t == 0) ? dec + ((long)b * J_ + j) * H_
                                    : emb + (long)teacher[((long)b * J_ + j) * K_ + (t - 1)] * H_;
        f16* dst = Wall + (long)r * H_;
        for (int c = threadIdx.x; c < H_; c += 256) dst[c] = (f16)src[c];
    } else {
        const long n = (long)H3 * H_;
        for (long i = (long)(r - R_) * 256 + threadIdx.x; i < n; i += (long)CASTB * 256)
            wih16[i] = (f16)wih[i];
    }
}

// h exchange word: {seq:32 | f32 bits:32}; chain-major [chain][parity][768].
// Writes BOTH parities every call (replay-deterministic).
__global__ void k_init_h(const float* __restrict__ hidden, ull* __restrict__ hbuf) {
    int i = blockIdx.x * 256 + threadIdx.x;
    if (i < B_ * H_) {
        int b = i / H_, u = i % H_;
        hbuf[(long)b * 1536 + u] = (ull)__float_as_uint(hidden[i]);  // seq 0, parity 0
        hbuf[(long)b * 1536 + 768 + u] = 0;                          // parity 1 cleared
    }
}

// ---------------------------------------------------------------- shared GEMM helpers
typedef const __attribute__((address_space(1))) unsigned GASU;
typedef __attribute__((address_space(3))) unsigned LASU;
__device__ __forceinline__ void gld16(const f16* g, f16* l) {
    __builtin_amdgcn_global_load_lds((GASU*)g, (LASU*)l, 16, 0, 0);
}

// ---------------------------------------------------------------- f16 MFMA GEMM (m97 structure)
// C[M,N] = A[M,K] @ B[N,K]^T ; MODE 0: store, 1: store + bias[col]
template <int MODE>
__global__ __launch_bounds__(256) void k_gemm(const f16* __restrict__ A, const f16* __restrict__ Bm,
                                              float* __restrict__ C, const float* __restrict__ bias,
                                              int M, int N, int K, long sA, long sB, long sC) {
    A += (long)blockIdx.z * sA;
    Bm += (long)blockIdx.z * sB;
    C += (long)blockIdx.z * sC;
    const int m0 = blockIdx.y * 128, n0 = blockIdx.x * 128;
    __shared__ f16 As[128 * 32];
    __shared__ f16 Bs[128 * 32];
    const int tid = threadIdx.x, lane = tid & 63, wave = tid >> 6;
    const int wm = wave >> 1, wn = wave & 1;
    const int fr = lane & 15, kg = lane >> 4;
    f32x4 acc[4][4] = {};
    const int idxu = wave * 128;
    const int i0 = idxu + lane, i1 = idxu + 64 + lane;
    const int r0 = i0 >> 2, k80 = i0 & 3;
    const int r1 = i1 >> 2, k81 = i1 & 3;
    int ga0 = m0 + r0; if (ga0 >= M) ga0 = M - 1;
    int ga1 = m0 + r1; if (ga1 >= M) ga1 = M - 1;
    int gb0 = n0 + r0; if (gb0 >= N) gb0 = N - 1;
    int gb1 = n0 + r1; if (gb1 >= N) gb1 = N - 1;
    const f16* pa0 = A + (long)ga0 * K + k80 * 8;
    const f16* pa1 = A + (long)ga1 * K + k81 * 8;
    const f16* pb0 = Bm + (long)gb0 * K + k80 * 8;
    const f16* pb1 = Bm + (long)gb1 * K + k81 * 8;
    for (int kt = 0; kt < K; kt += 32) {
        gld16(pa0 + kt, As + idxu * 8);
        gld16(pa1 + kt, As + idxu * 8 + 512);
        gld16(pb0 + kt, Bs + idxu * 8);
        gld16(pb1 + kt, Bs + idxu * 8 + 512);
        __syncthreads();
        f16x8 af[4], bf[4];
#pragma unroll
        for (int m = 0; m < 4; ++m) af[m] = *(const f16x8*)(As + (wm * 64 + m * 16 + fr) * 32 + kg * 8);
#pragma unroll
        for (int n = 0; n < 4; ++n) bf[n] = *(const f16x8*)(Bs + (wn * 64 + n * 16 + fr) * 32 + kg * 8);
#pragma unroll
        for (int m = 0; m < 4; ++m)
#pragma unroll
            for (int n = 0; n < 4; ++n)
                acc[m][n] = __builtin_amdgcn_mfma_f32_16x16x32_f16(af[m], bf[n], acc[m][n], 0, 0, 0);
        __syncthreads();
    }
    const int crow = m0 + wm * 64 + (lane >> 4) * 4;
    const int ccol = n0 + wn * 64 + fr;
#pragma unroll
    for (int n = 0; n < 4; ++n) {
        int col = ccol + n * 16;
        if (col >= N) continue;
        float bv = (MODE == 1) ? bias[col] : 0.f;
#pragma unroll
        for (int m = 0; m < 4; ++m) {
#pragma unroll
            for (int q = 0; q < 4; ++q) {
                int row = crow + m * 16 + q;
                if (row < M) C[(long)row * N + col] = acc[m][n][q] + bv;
            }
        }
    }
}

// ---------------------------------------------------------------- merged hi/lo attention logits
__global__ __launch_bounds__(256) void k_attn3(const f16* __restrict__ Ahi, const f16* __restrict__ Alo,
                                               const f16* __restrict__ Bhi, const f16* __restrict__ Blo,
                                               float* __restrict__ C, int M, int N, int K,
                                               long sA, long sB, long sC) {
    const long za = (long)blockIdx.z * sA, zb = (long)blockIdx.z * sB;
    C += (long)blockIdx.z * sC;
    const int m0 = blockIdx.y * 128, n0 = blockIdx.x * 128;
    __shared__ f16 As[128 * 32];
    __shared__ f16 Bs[128 * 32];
    const int tid = threadIdx.x, lane = tid & 63, wave = tid >> 6;
    const int wm = wave >> 1, wn = wave & 1;
    const int fr = lane & 15, kg = lane >> 4;
    f32x4 acc[4][4] = {};
    const int idxu = wave * 128;
    const int i0 = idxu + lane, i1 = idxu + 64 + lane;
    const int r0 = i0 >> 2, k80 = i0 & 3;
    const int r1 = i1 >> 2, k81 = i1 & 3;
    int ga0 = m0 + r0; if (ga0 >= M) ga0 = M - 1;
    int ga1 = m0 + r1; if (ga1 >= M) ga1 = M - 1;
    int gb0 = n0 + r0; if (gb0 >= N) gb0 = N - 1;
    int gb1 = n0 + r1; if (gb1 >= N) gb1 = N - 1;
    const long oa0 = (long)ga0 * K + k80 * 8, oa1 = (long)ga1 * K + k81 * 8;
    const long ob0 = (long)gb0 * K + k80 * 8, ob1 = (long)gb1 * K + k81 * 8;
    for (int ph = 0; ph < 3; ++ph) {
        const f16* Ap = (ph == 2 ? Alo : Ahi) + za;
        const f16* Bp = (ph == 1 ? Blo : Bhi) + zb;
        for (int kt = 0; kt < K; kt += 32) {
            gld16(Ap + oa0 + kt, As + idxu * 8);
            gld16(Ap + oa1 + kt, As + idxu * 8 + 512);
            gld16(Bp + ob0 + kt, Bs + idxu * 8);
            gld16(Bp + ob1 + kt, Bs + idxu * 8 + 512);
            __syncthreads();
            f16x8 af[4], bf[4];
#pragma unroll
            for (int m = 0; m < 4; ++m) af[m] = *(const f16x8*)(As + (wm * 64 + m * 16 + fr) * 32 + kg * 8);
#pragma unroll
            for (int n = 0; n < 4; ++n) bf[n] = *(const f16x8*)(Bs + (wn * 64 + n * 16 + fr) * 32 + kg * 8);
#pragma unroll
            for (int m = 0; m < 4; ++m)
#pragma unroll
                for (int n = 0; n < 4; ++n)
                    acc[m][n] = __builtin_amdgcn_mfma_f32_16x16x32_f16(af[m], bf[n], acc[m][n], 0, 0, 0);
            __syncthreads();
        }
    }
    const int crow = m0 + wm * 64 + (lane >> 4) * 4;
    const int ccol = n0 + wn * 64 + fr;
#pragma unroll
    for (int n = 0; n < 4; ++n) {
        int col = ccol + n * 16;
        if (col >= N) continue;
#pragma unroll
        for (int m = 0; m < 4; ++m) {
#pragma unroll
            for (int q = 0; q < 4; ++q) {
                int row = crow + m * 16 + q;
                if (row < M) C[(long)row * N + col] = acc[m][n][q];
            }
        }
    }
}

// ---------------------------------------------------------------- vocab GEMM
// BF16OUT=0: Cf = exp(...) f32. BF16OUT=1: Ch = bf16(exp(...)) u16.
// Both: per-tile row partial sums (f32, pre-rounding) -> psum[nt][row].
template <int BF16OUT>
__global__ __launch_bounds__(256) void k_vocab(const f16* __restrict__ A, const f16* __restrict__ Bm,
                                               float* __restrict__ Cf, unsigned short* __restrict__ Ch,
                                               float* __restrict__ psum) {
    const int M = R_, N = V_, K = H_;
    const int nwg = VMT * VNT;
    int lin = blockIdx.x;
    int q8 = nwg / 8, r8 = nwg % 8;
    int xcd = lin & 7, idx = lin >> 3;
    int newlin = (xcd < r8) ? xcd * (q8 + 1) + idx : r8 * (q8 + 1) + (xcd - r8) * q8 + idx;
    int mt = newlin % VMT, nt = newlin / VMT;
    const int m0 = mt * 128, n0 = nt * 128;
    __shared__ f16 As[128 * 32];
    __shared__ f16 Bs[128 * 32];
    __shared__ float rpart[2][128];
    const int tid = threadIdx.x, lane = tid & 63, wave = tid >> 6;
    const int wm = wave >> 1, wn = wave & 1;
    const int fr = lane & 15, kg = lane >> 4;
    f32x4 acc[4][4] = {};
    const int idxu = wave * 128;
    const int i0 = idxu + lane, i1 = idxu + 64 + lane;
    const int r0 = i0 >> 2, k80 = i0 & 3;
    const int r1 = i1 >> 2, k81 = i1 & 3;
    int ga0 = m0 + r0; if (ga0 >= M) ga0 = M - 1;
    int ga1 = m0 + r1; if (ga1 >= M) ga1 = M - 1;
    int gb0 = n0 + r0; if (gb0 >= N) gb0 = N - 1;
    int gb1 = n0 + r1; if (gb1 >= N) gb1 = N - 1;
    const f16* pa0 = A + (long)ga0 * K + k80 * 8;
    const f16* pa1 = A + (long)ga1 * K + k81 * 8;
    const f16* pb0 = Bm + (long)gb0 * K + k80 * 8;
    const f16* pb1 = Bm + (long)gb1 * K + k81 * 8;
    for (int kt = 0; kt < K; kt += 32) {
        gld16(pa0 + kt, As + idxu * 8);
        gld16(pa1 + kt, As + idxu * 8 + 512);
        gld16(pb0 + kt, Bs + idxu * 8);
        gld16(pb1 + kt, Bs + idxu * 8 + 512);
        __syncthreads();
        f16x8 af[4], bf[4];
#pragma unroll
        for (int m = 0; m < 4; ++m) af[m] = *(const f16x8*)(As + (wm * 64 + m * 16 + fr) * 32 + kg * 8);
#pragma unroll
        for (int n = 0; n < 4; ++n) bf[n] = *(const f16x8*)(Bs + (wn * 64 + n * 16 + fr) * 32 + kg * 8);
#pragma unroll
        for (int m = 0; m < 4; ++m)
#pragma unroll
            for (int n = 0; n < 4; ++n)
                acc[m][n] = __builtin_amdgcn_mfma_f32_16x16x32_f16(af[m], bf[n], acc[m][n], 0, 0, 0);
        __syncthreads();
    }
    const int crow = m0 + wm * 64 + (lane >> 4) * 4;
    const int ccol = n0 + wn * 64 + fr;
    float rs[4][4];
#pragma unroll
    for (int m = 0; m < 4; ++m)
#pragma unroll
        for (int q = 0; q < 4; ++q) rs[m][q] = 0.f;
#pragma unroll
    for (int n = 0; n < 4; ++n) {
        int col = ccol + n * 16;
        if (col >= N) continue;
#pragma unroll
        for (int m = 0; m < 4; ++m) {
#pragma unroll
            for (int q = 0; q < 4; ++q) {
                int row = crow + m * 16 + q;
                if (row < M) {
                    float e = __expf(acc[m][n][q]);
                    if (BF16OUT) {
                        unsigned uu = __float_as_uint(e);
                        uu += 0x7FFFu + ((uu >> 16) & 1u);   // RNE to bf16
                        Ch[(long)row * N + col] = (unsigned short)(uu >> 16);
                    } else {
                        Cf[(long)row * N + col] = e;
                    }
                    rs[m][q] += e;
                }
            }
        }
    }
#pragma unroll
    for (int m = 0; m < 4; ++m)
#pragma unroll
        for (int q = 0; q < 4; ++q) {
            float v = rs[m][q];
            v += __shfl_xor(v, 1);
            v += __shfl_xor(v, 2);
            v += __shfl_xor(v, 4);
            v += __shfl_xor(v, 8);
            rs[m][q] = v;
        }
    if ((lane & 15) == 0) {
#pragma unroll
        for (int m = 0; m < 4; ++m)
#pragma unroll
            for (int q = 0; q < 4; ++q)
                rpart[wn][wm * 64 + (lane >> 4) * 4 + m * 16 + q] = rs[m][q];
    }
    __syncthreads();
    if (tid < 128) {
        int row = m0 + tid;
        if (row < M) psum[(long)nt * M + row] = rpart[0][tid] + rpart[1][tid];
    }
}

// ---------------------------------------------------------------- GRU recurrence + hidden preps (R15/R17-proven)
__device__ __forceinline__ float fd2(unsigned hv, unsigned wv, float acc) {
#if __has_builtin(__builtin_amdgcn_fdot2)
    return __builtin_amdgcn_fdot2(__builtin_bit_cast(h2, hv), __builtin_bit_cast(h2, wv), acc, false);
#else
    h2 a = __builtin_bit_cast(h2, hv), b = __builtin_bit_cast(h2, wv);
    return acc + (float)a.x * (float)b.x + (float)a.y * (float)b.y;
#endif
}

__global__ __launch_bounds__(256, 1) void k_gru(const float* __restrict__ gi,
                                                const float* __restrict__ whh,
                                                const float* __restrict__ bhh,
                                                ull* hbuf,
                                                f16* __restrict__ Hhi, f16* __restrict__ Hlo,
                                                const float* __restrict__ emb, f16* __restrict__ emb16,
                                                const float* __restrict__ enc, f16* __restrict__ ehi,
                                                f16* __restrict__ elo, f16* __restrict__ encT) {
    __shared__ ui4v wsvu[9216];               // weights (recurrence) / transpose tile (prep)
    __shared__ __align__(16) f16 hsf[768];
    __shared__ float part[2][8][32][3];       // [parity][octant][unit][gate] (0 conflicts)
    const int tid = threadIdx.x;
    if (blockIdx.x >= 192) {
        // ---------- hidden prep on idle CUs ----------
        const long pt = (long)(blockIdx.x - 192) * 256 + tid;
        const long n4 = (long)V_ * H_ / 4;
        for (long i = pt; i < n4; i += 64 * 256) {
            f32x4 v = ((const f32x4*)emb)[i];
            f16x4v r = {(f16)v.x, (f16)v.y, (f16)v.z, (f16)v.w};
            ((f16x4v*)emb16)[i] = r;
        }
        const long n4e = (long)B_ * S_ * H_ / 4;
        for (long i = pt; i < n4e; i += 64 * 256) {
            f32x4 v = ((const f32x4*)enc)[i];
            f16 h0 = (f16)v.x, h1 = (f16)v.y, h2v = (f16)v.z, h3 = (f16)v.w;
            f16x4v hv = {h0, h1, h2v, h3};
            ((f16x4v*)ehi)[i] = hv;
            f16x4v lv = {(f16)(v.x - (float)h0), (f16)(v.y - (float)h1),
                         (f16)(v.z - (float)h2v), (f16)(v.w - (float)h3)};
            ((f16x4v*)elo)[i] = lv;
        }
        // encT via LDS-tiled transpose (64x64 f32 tile, pad 65)
        float* tl = (float*)wsvu;
        for (int t = blockIdx.x - 192; t < 8 * 8 * 12; t += 64) {
            int ht = t % 12, st = (t / 12) % 8, bb = t / 96;
            __syncthreads();
#pragma unroll
            for (int k = 0; k < 16; ++k) {
                int i = tid + k * 256;
                int sl = i >> 6, hl = i & 63;
                tl[sl * 65 + hl] = enc[((long)bb * S_ + st * 64 + sl) * H_ + ht * 64 + hl];
            }
            __syncthreads();
#pragma unroll
            for (int k = 0; k < 16; ++k) {
                int i = tid + k * 256;
                int hl = i >> 6, sl = i & 63;
                encT[((long)bb * H_ + ht * 64 + hl) * S_ + st * 64 + sl] = (f16)tl[sl * 65 + hl];
            }
        }
        return;
    }
    // ---------- recurrence ----------
    const int chain = blockIdx.x / 24;
    const int blk = blockIdx.x % 24;
    const int u0 = blk * 32;
    for (int idx = tid; idx < 9216; idx += 256) {
        int uu = idx & 31, k8 = (idx >> 5) % 96, g = idx / (96 * 32);
        const float* src = whh + (long)(g * H_ + u0 + uu) * H_ + k8 * 8;
        f32x4 a = *(const f32x4*)src;
        f32x4 b2 = *(const f32x4*)(src + 4);
        f16x8 pk = {(f16)a.x, (f16)a.y, (f16)a.z, (f16)a.w,
                    (f16)b2.x, (f16)b2.y, (f16)b2.z, (f16)b2.w};
        wsvu[idx] = __builtin_bit_cast(ui4v, pk);
    }
    float b_r = 0.f, b_z = 0.f, b_n = 0.f;
    if (tid < 32) {
        int c = u0 + tid;
        b_r = bhh[c];
        b_z = bhh[H_ + c];
        b_n = bhh[2 * H_ + c];
    }
    __syncthreads();
    const int u = tid & 31, q = tid >> 5, lane = tid & 63;
    const int pw = (tid >> 6) * 192 + lane;   // this wave's h-word base
    ui4v wreg[3][12];
#pragma unroll
    for (int g = 0; g < 3; ++g)
#pragma unroll
        for (int i = 0; i < 12; ++i)
            wreg[g][i] = wsvu[(g * 96 + q * 12 + i) * 32 + u];
    ull* base = hbuf + (long)chain * 1536;
    const bool fin = (tid < 32);
    float g0 = 0.f, g1 = 0.f, g2v = 0.f;
    if (fin) {
        const float* gp = gi + (long)chain * 270 * H3;
        int c = u0 + tid;
        g0 = gp[c];
        g1 = gp[H_ + c];
        g2v = gp[2 * H_ + c];
    }
    for (int s = 0; s < 270; ++s) {
        const ull* rb = base + (s & 1) * 768;
        ull* wb = base + ((s + 1) & 1) * 768;
        const unsigned want = (unsigned)s;
        ull v0, v1, v2, vh = 0;
        for (;;) {
            v0 = ALD(rb + pw);
            v1 = ALD(rb + pw + 64);
            v2 = ALD(rb + pw + 128);
            bool ok = ((unsigned)(v0 >> 32) == want) & ((unsigned)(v1 >> 32) == want) &
                      ((unsigned)(v2 >> 32) == want);
            if (fin) {
                vh = ALD(rb + u0 + tid);
                ok &= ((unsigned)(vh >> 32) == want);
            }
            if (ok) break;
        }
        hsf[pw] = (f16)__uint_as_float((unsigned)v0);
        hsf[pw + 64] = (f16)__uint_as_float((unsigned)v1);
        hsf[pw + 128] = (f16)__uint_as_float((unsigned)v2);
        __builtin_amdgcn_wave_barrier();
        float ar = 0.f, az = 0.f, an = 0.f;
#pragma unroll
        for (int i = 0; i < 12; ++i) {
            ui4v hv = *(const ui4v*)(&hsf[(q * 12 + i) * 8]);
            ui4v wr = wreg[0][i], wz = wreg[1][i], wn = wreg[2][i];
            ar = fd2(hv.x, wr.x, ar); ar = fd2(hv.y, wr.y, ar);
            ar = fd2(hv.z, wr.z, ar); ar = fd2(hv.w, wr.w, ar);
            az = fd2(hv.x, wz.x, az); az = fd2(hv.y, wz.y, az);
            az = fd2(hv.z, wz.z, az); az = fd2(hv.w, wz.w, az);
            an = fd2(hv.x, wn.x, an); an = fd2(hv.y, wn.y, an);
            an = fd2(hv.z, wn.z, an); an = fd2(hv.w, wn.w, an);
        }
        const int par = s & 1;
        part[par][q][u][0] = ar;
        part[par][q][u][1] = az;
        part[par][q][u][2] = an;
        __syncthreads();                       // B: partials ready (block-wide)
        if (fin) {
            float gr = b_r, gz = b_z, gn = b_n;
#pragma unroll
            for (int qq = 0; qq < 8; ++qq) {
                gr += part[par][qq][tid][0];
                gz += part[par][qq][tid][1];
                gn += part[par][qq][tid][2];
            }
            float hold = __uint_as_float((unsigned)vh);
            float rg = 1.f / (1.f + __expf(-(g0 + gr)));
            float zg = 1.f / (1.f + __expf(-(g1 + gz)));
            float xa = g2v + rg * gn;
            float e2 = __expf(-2.f * xa);
            float ng = (1.f - e2) / (1.f + e2);
            float hnew = (1.f - zg) * ng + zg * hold;
            int c = u0 + tid;
            ull wvv = ((ull)(unsigned)(s + 1) << 32) | (ull)__float_as_uint(hnew);
            AST(wb + c, wvv);
            long row = (long)chain * 270 + s;
            f16 h16 = (f16)hnew;
            Hhi[row * H_ + c] = h16;
            Hlo[row * H_ + c] = (f16)(hnew - (float)h16);
            if (s < 269) {   // prefetch next step's gi (hidden behind next poll)
                const float* gp = gi + ((long)chain * 270 + s + 1) * H3;
                g0 = gp[c];
                g1 = gp[H_ + c];
                g2v = gp[2 * H_ + c];
            }
        }
    }
}

// ---------------------------------------------------------------- attention softmax
__global__ __launch_bounds__(256) void k_attn_softmax(const float* __restrict__ lg,
                                                      const int* __restrict__ x, f16* __restrict__ ah) {
    __shared__ float red[256];
    int r = blockIdx.x, tid = threadIdx.x;
    int b = r / 270;
    const float* lr = lg + (long)r * S_;
    const int* xb = x + (long)b * S_;
    float v0 = lr[tid];
    if (xb[tid] == 0) v0 = -1e9f;
    float v1 = lr[tid + 256];
    if (xb[tid + 256] == 0) v1 = -1e9f;
    red[tid] = fmaxf(v0, v1);
    __syncthreads();
    for (int o = 128; o > 0; o >>= 1) {
        if (tid < o) red[tid] = fmaxf(red[tid], red[tid + o]);
        __syncthreads();
    }
    float m = red[0];
    __syncthreads();
    float e0 = __expf(v0 - m), e1 = __expf(v1 - m);
    red[tid] = e0 + e1;
    __syncthreads();
    for (int o = 128; o > 0; o >>= 1) {
        if (tid < o) red[tid] += red[tid + o];
        __syncthreads();
    }
    float inv = 1.f / red[0];
    ah[(long)r * S_ + tid] = (f16)(e0 * inv);
    ah[(long)r * S_ + tid + 256] = (f16)(e1 * inv);
}

// ---------------------------------------------------------------- fused p_gen + rinv + finalize + scatter
// TWO blocks per row (half-row each, 70KB LDS -> 2 blocks/CU). BF16: read u16
// exp temp; else read f32 exp from out in place. Scatter predicated on v-range.
template <int BF16>
__global__ __launch_bounds__(256, 2) void k_fin3(float* __restrict__ out,
                                                 const float* __restrict__ psum,
                                                 const unsigned short* __restrict__ expv,
                                                 const f16* __restrict__ Wall,
                                                 const f16* __restrict__ Hhi,
                                                 const f16* __restrict__ Hlo,
                                                 const float* __restrict__ ctx,
                                                 const float* __restrict__ wg,
                                                 const float* __restrict__ wgb,
                                                 const f16* __restrict__ ah,
                                                 const int* __restrict__ x) {
    __shared__ float row[VH0];
    __shared__ float red[256], red2[256];
    const int r = blockIdx.x >> 1, half = blockIdx.x & 1;
    const int tid = threadIdx.x;
    const int b = r / 270;
    const int lo = half ? VH0 : 0;
    const int len = half ? (V_ - VH0) : VH0;      // 17500 / 17504, both %4==0
    float a = 0.f;
    for (int i = tid; i < H_; i += 256) {
        a += (float)Wall[(long)r * H_ + i] * wg[i];
        a += ((float)Hhi[(long)r * H_ + i] + (float)Hlo[(long)r * H_ + i]) * wg[H_ + i];
        a += ctx[(long)r * H_ + i] * wg[2 * H_ + i];
    }
    float s = 0.f;
    for (int i = tid; i < VNT; i += 256) s += psum[(long)i * R_ + r];
    red[tid] = s;
    red2[tid] = a;
    __syncthreads();
    for (int o = 128; o > 0; o >>= 1) {
        if (tid < o) {
            red[tid] += red[tid + o];
            red2[tid] += red2[tid + o];
        }
        __syncthreads();
    }
    const float pgv = 1.f / (1.f + __expf(-(red2[0] + wgb[0])));
    const float scale = pgv / red[0];
    const int n4 = len / 4;
    if (BF16) {
        const unsigned short* ep = expv + (long)r * V_ + lo;
        for (int i = tid; i < n4; i += 256) {
            u16x4 v = ((const u16x4*)ep)[i];
            f32x4 o;
            o.x = __uint_as_float((unsigned)v.x << 16) * scale;
            o.y = __uint_as_float((unsigned)v.y << 16) * scale;
            o.z = __uint_as_float((unsigned)v.z << 16) * scale;
            o.w = __uint_as_float((unsigned)v.w << 16) * scale;
            ((f32x4*)row)[i] = o;
        }
    } else {
        const float* op = out + (long)r * V_ + lo;
        for (int i = tid; i < n4; i += 256) {
            f32x4 v = ((const f32x4*)op)[i];
            v.x *= scale;
            v.y *= scale;
            v.z *= scale;
            v.w *= scale;
            ((f32x4*)row)[i] = v;
        }
    }
    __syncthreads();
    const float om = 1.f - pgv;
    for (int s2 = tid; s2 < S_; s2 += 256) {
        int xv = x[(long)b * S_ + s2];
        if (xv != 0 && xv >= lo && xv < lo + len) {
            float av = (float)ah[(long)r * S_ + s2];
            if (av != 0.f) atomicAdd(&row[xv - lo], om * av);
        }
    }
    __syncthreads();
    float* orow = out + (long)r * V_ + lo;
    for (int i = tid; i < n4; i += 256)
        ((f32x4*)orow)[i] = ((const f32x4*)row)[i];
}

// ---------------------------------------------------------------- host
extern "C" void kernel_launch(void* const* d_in, const int* in_sizes, int n_in, void* d_out,
                              int out_size, void* d_ws, size_t ws_size, hipStream_t stream) {
    (void)in_sizes; (void)n_in; (void)out_size;
    const int* x = (const int*)d_in[0];
    const float* dec = (const float*)d_in[1];
    const float* enc = (const float*)d_in[2];
    const float* hid = (const float*)d_in[3];
    const int* tea = (const int*)d_in[4];
    const float* emb = (const float*)d_in[6];
    const float* wih = (const float*)d_in[7];
    const float* whh = (const float*)d_in[8];
    const float* bih = (const float*)d_in[9];
    const float* bhh = (const float*)d_in[10];
    const float* wgw = (const float*)d_in[11];
    const float* wgb = (const float*)d_in[12];
    float* out = (float*)d_out;

    char* w = (char*)d_ws;
    size_t off = 0;
    auto alloc = [&](size_t bytes) {
        void* p = w + off;
        off = (off + bytes + 255) & ~(size_t)255;
        return p;
    };
    // ---- live-through-finalize buffers first ----
    ull* hbuf = (ull*)alloc(8 * 1536 * 8);
    f16* Wall = (f16*)alloc((size_t)R_ * H_ * 2);
    f16* Hhi = (f16*)alloc((size_t)R_ * H_ * 2);
    f16* Hlo = (f16*)alloc((size_t)R_ * H_ * 2);
    f16* emb16 = (f16*)alloc((size_t)V_ * H_ * 2);
    f16* ah = (f16*)alloc((size_t)R_ * S_ * 2);
    float* ctx = (float*)alloc((size_t)R_ * H_ * 4);
    float* psum = (float*)alloc((size_t)VNT * R_ * 4);
    // ---- dead-after-midpipe buffers (aliasable by expv) ----
    const size_t deadbase = off;
    f16* wih16 = (f16*)alloc((size_t)H3 * H_ * 2);
    float* giA = (float*)alloc((size_t)R_ * H3 * 4);
    f16* ehi = (f16*)alloc((size_t)B_ * S_ * H_ * 2);
    f16* elo = (f16*)alloc((size_t)B_ * S_ * H_ * 2);
    f16* encT = (f16*)alloc((size_t)B_ * H_ * S_ * 2);
    float* lgH = (float*)alloc((size_t)R_ * S_ * 4);
    // expv aliases the dead region (only used after all dead buffers retire)
    unsigned short* expv = (unsigned short*)(w + deadbase);
    const bool fused = (deadbase + (size_t)R_ * V_ * 2 <= ws_size);

    k_init_h<<<24, 256, 0, stream>>>(hid, hbuf);
    k_prep<<<R_ + CASTB, 256, 0, stream>>>(emb, dec, tea, Wall, wih, wih16);

    // gi = W_all @ w_ih^T + b_ih
    {
        dim3 g(H3 / 128, (R_ + 127) / 128, 1);
        k_gemm<1><<<g, 256, 0, stream>>>(Wall, wih16, giA, bih, R_, H3, H_, 0, 0, 0);
    }
    // recurrence (blocks 0-191) + hidden preps on idle CUs (blocks 192-255)
    k_gru<<<256, 256, 0, stream>>>(giA, whh, bhh, hbuf, Hhi, Hlo,
                                   emb, emb16, enc, ehi, elo, encT);

    // attention logits (merged hi/lo): Hhi*Ehi + Hhi*Elo + Hlo*Ehi
    {
        dim3 g(S_ / 128, 3, 8);
        k_attn3<<<g, 256, 0, stream>>>(Hhi, Hlo, ehi, elo, lgH, 270, S_, H_,
                                       270L * H_, (long)S_ * H_, 270L * S_);
    }
    k_attn_softmax<<<R_, 256, 0, stream>>>(lgH, x, ah);
    {
        dim3 g(H_ / 128, 3, 8);
        k_gemm<0><<<g, 256, 0, stream>>>(ah, encT, ctx, nullptr, 270, H_, S_, 270L * S_, (long)H_ * S_, 270L * H_);
    }

    if (fused) {
        k_vocab<1><<<VMT * VNT, 256, 0, stream>>>(Hhi, emb16, nullptr, expv, psum);
        k_fin3<1><<<2 * R_, 256, 0, stream>>>(out, psum, expv, Wall, Hhi, Hlo, ctx, wgw, wgb, ah, x);
    } else {
        k_vocab<0><<<VMT * VNT, 256, 0, stream>>>(Hhi, emb16, out, nullptr, psum);
        k_fin3<0><<<2 * R_, 256, 0, stream>>>(out, psum, nullptr, Wall, Hhi, Hlo, ctx, wgw, wgb, ah, x);
    }
}